// Round 4
// baseline (530.113 us; speedup 1.0000x reference)
//
#include <hip/hip_runtime.h>

// Convert2Image: out[b,h,w,:] = lstm[b, slic[b,h,w]-1, :]
// B=4, S=256, C=128, H=W=512. fp32 in/out.
// 512 MiB written, ~4.5 MiB effectively read (cache-absorbed).
//
// v4: v3 minus non-temporal stores (single-variable A/B).
//   Evidence: the harness's fillBufferAligned sustains 6.2 TB/s at 10%
//   occupancy through the normal L2 write path; our nt-store stream runs at
//   exactly half that. Theory: nt stores bypass L2 write aggregation and
//   bottleneck at the HBM write controllers; plain stores ride the same
//   path as the 6.2 TB/s fill. lstm table (512 KiB) re-fetches from L3
//   nearly free if the write stream partially thrashes L2.
//   - persistent grid-stride, 2048 blocks x 256 threads
//   - per tile: 8 float4/thread; pipeline: gathers(t) -> slic(t+1) ->
//     stores(t) -> addrs(t+1)
// All dims are powers of two: C/4 = 32 = 2^5, H*W = 2^18, S = 2^8.

typedef float f32x4 __attribute__((ext_vector_type(4)));

constexpr int C4       = 32;     // C/4 float4 per pixel
constexpr int LOG_C4   = 5;
constexpr int LOG_HW   = 18;     // H*W = 262144
constexpr int LOG_S    = 8;      // S = 256
constexpr int UNROLL   = 8;      // float4 per thread per tile
constexpr int BLK      = 256;
constexpr int TILE     = BLK * UNROLL;   // 2048 float4 = 64 pixels = 32 KiB out
constexpr int LOG_TILE = 11;
constexpr int MAXGRID  = 2048;   // 8 blocks/CU; grid-stride the rest

__global__ __launch_bounds__(BLK)
void convert2image_kernel(const f32x4* __restrict__ lstm,  // [B*S*C4]
                          const int*   __restrict__ slic,  // [B*H*W], 1-based
                          f32x4*       __restrict__ out,   // [B*H*W*C4]
                          int n4)
{
    const int n_tiles = n4 >> LOG_TILE;
    const int t       = threadIdx.x;

    if ((int)blockIdx.x < n_tiles) {
        int tile   = blockIdx.x;
        int stride = gridDim.x;
        int base   = tile * TILE + t;

        // ---- prologue: slic + addresses for first tile ----
        int src[UNROLL];
        {
            int sg[UNROLL];
            #pragma unroll
            for (int u = 0; u < UNROLL; ++u)
                sg[u] = slic[(base + u * BLK) >> LOG_C4];
            #pragma unroll
            for (int u = 0; u < UNROLL; ++u) {
                int i  = base + u * BLK;
                int c4 = i & (C4 - 1);
                int b  = i >> (LOG_C4 + LOG_HW);
                src[u] = (((b << LOG_S) + (sg[u] - 1)) << LOG_C4) + c4;
            }
        }

        for (;;) {
            const int  next  = tile + stride;
            const bool more  = next < n_tiles;
            const int  nbase = next * TILE + t;

            // 1) issue gathers for current tile (oldest in vmcnt FIFO)
            f32x4 v[UNROLL];
            #pragma unroll
            for (int u = 0; u < UNROLL; ++u)
                v[u] = lstm[src[u]];

            // 2) issue slic loads for NEXT tile — independent of the gathers,
            //    younger in the FIFO, so waiting for gathers leaves them in flight
            int nsg[UNROLL];
            if (more) {
                #pragma unroll
                for (int u = 0; u < UNROLL; ++u)
                    nsg[u] = slic[(nbase + u * BLK) >> LOG_C4];
            }

            // 3) store current tile (plain stores — ride the L2 write path)
            #pragma unroll
            for (int u = 0; u < UNROLL; ++u)
                out[base + u * BLK] = v[u];

            if (!more) break;

            // 4) compute next tile's gather addresses (slic wait overlaps stores)
            #pragma unroll
            for (int u = 0; u < UNROLL; ++u) {
                int i  = nbase + u * BLK;
                int c4 = i & (C4 - 1);
                int b  = i >> (LOG_C4 + LOG_HW);
                src[u] = (((b << LOG_S) + (nsg[u] - 1)) << LOG_C4) + c4;
            }
            base = nbase;
            tile = next;
        }
    }

    // ---- tail (n4 not a multiple of TILE; no-op for this shape) ----
    if (blockIdx.x == 0) {
        for (int i = (n_tiles << LOG_TILE) + t; i < n4; i += BLK) {
            int c4  = i & (C4 - 1);
            int pix = i >> LOG_C4;
            int b   = pix >> LOG_HW;
            int seg = slic[pix] - 1;
            out[i] = lstm[(((b << LOG_S) + seg) << LOG_C4) + c4];
        }
    }
}

extern "C" void kernel_launch(void* const* d_in, const int* in_sizes, int n_in,
                              void* d_out, int out_size, void* d_ws, size_t ws_size,
                              hipStream_t stream) {
    const f32x4* lstm = (const f32x4*)d_in[0];   // graph_lstm_output [4,256,128] f32
    const int*   slic = (const int*)d_in[1];     // slic_output [4,512,512] i32
    f32x4*       out  = (f32x4*)d_out;           // [4,512,512,128] f32

    int n4      = out_size / 4;                  // 33,554,432 float4 elements
    int n_tiles = n4 >> LOG_TILE;                // 16,384 tiles
    int blocks  = n_tiles < MAXGRID ? (n_tiles > 0 ? n_tiles : 1) : MAXGRID;
    convert2image_kernel<<<blocks, BLK, 0, stream>>>(lstm, slic, out, n4);
}